// Round 2
// 297.513 us; speedup vs baseline: 1.0058x; 1.0058x over previous
//
#include <hip/hip_runtime.h>

// Sparse graph attention (fp32).
// Build v4 (resubmit — round-1 failure was an MI355X container flake, not a
// kernel verdict): p2 stages its row-bucket window in LDS (random 4B stores
// to global were ~1.6M uncoalesced fabric transactions ~= 110us at the
// measured 14-15G trans/s rate; LDS absorbs them at per-CU rates) and
// blasts the window out with coalesced int4 stores. Each partition is
// split across 2 blocks (128 rows, 33KB LDS -> 4 blocks/CU), re-reading
// the part list twice (cheap, coalesced). Blast is clamped at n_nodes so
// the tail partition cannot overwrite the part array.
// Row kernel v2: 16 edges in flight per wave (was 8) -> 12 outstanding
// gather loads; counters showed latency-bound (VALUBusy 29%, 45% BW,
// occupancy 79%), so 2x MLP should move BW toward ~5 TB/s.
// Tiered ws fallback unchanged: >=35.2MB new path; >=26MB direct scatter;
// else round-4 fused atomic path.

#define HD 64
#define ED 32
#define CAP 64          // bucket slots per row
#define RPP 256         // rows per partition
#define PSHIFT 8
#define D1 36           // pass-1 LDS bin depth
#define NB1 256         // pass-1 blocks
#define PCAP 5120       // partition list capacity (mean 4093 at E=1.6M)
#define SPILL_CAP 131072

// ---------------- pass 1: partition binning ----------------
__global__ void p1_bin_kernel(const int* __restrict__ idx, int n_edges,
                              int NP, int chunk,
                              int* __restrict__ part, int* __restrict__ gcur,
                              long long* __restrict__ spill,
                              int* __restrict__ spill_cnt,
                              int* __restrict__ flag) {
    extern __shared__ int sm[];          // [NP] cnt, then [NP*D1] bins
    int* cnt  = sm;
    int* bins = sm + NP;
    int tid = threadIdx.x;

    for (int i = tid; i < NP; i += 256) cnt[i] = 0;
    __syncthreads();

    int e0 = blockIdx.x * chunk;
    int n  = n_edges - e0; if (n > chunk) n = chunk; if (n < 0) n = 0;

    for (int i = tid; i < n; i += 256) {
        int e = e0 + i;
        int r = idx[e];
        int c = idx[n_edges + e];
        int p = r >> PSHIFT;
        int w = ((r & (RPP - 1)) << 17) | c;
        int pos = atomicAdd(&cnt[p], 1);         // LDS atomic
        if (pos < D1) {
            bins[p * D1 + pos] = w;
        } else {                                 // statistical overflow
            int s = atomicAdd(spill_cnt, 1);
            if (s < SPILL_CAP) spill[s] = ((long long)r << 32) | (unsigned)c;
            else *flag = 1;
        }
    }
    __syncthreads();

    // drain: each thread owns a few bins; contiguous burst per bin
    for (int p = tid; p < NP; p += 256) {
        int m = cnt[p]; if (m > D1) m = D1;
        if (m > 0) {
            int base = atomicAdd(&gcur[p], m);
            for (int j = 0; j < m; ++j) {
                int slot = base + j;
                int w = bins[p * D1 + j];
                if (slot < PCAP) {
                    part[p * PCAP + slot] = w;
                } else {
                    int r = (p << PSHIFT) | (w >> 17);
                    int c = w & 0x1FFFF;
                    int s = atomicAdd(spill_cnt, 1);
                    if (s < SPILL_CAP) spill[s] = ((long long)r << 32) | (unsigned)c;
                    else *flag = 1;
                }
            }
        }
    }
}

// ---------------- pass 2: per-half-partition LDS-staged bucket fill ------
// blockIdx.x = 2*p + half. Each block owns 128 rows of partition p,
// stages their 128x64 bucket window in LDS, then writes it out coalesced.
__global__ void p2_bucket_kernel(const int* __restrict__ part,
                                 const int* __restrict__ gcur,
                                 int* __restrict__ count,
                                 int* __restrict__ bucket, int n_nodes) {
    __shared__ int cnt[RPP / 2];          // 128 counters
    __shared__ int win[(RPP / 2) * CAP];  // 32KB staged window (uninit ok)
    int tid = threadIdx.x;
    if (tid < RPP / 2) cnt[tid] = 0;
    __syncthreads();

    int p    = blockIdx.x >> 1;
    int half = blockIdx.x & 1;
    int n = gcur[p]; if (n > PCAP) n = PCAP;

    for (int i = tid; i < n; i += 256) {
        int w  = part[p * PCAP + i];
        int rl = w >> 17;                       // 0..255 within partition
        if ((rl >> 7) != half) continue;        // other block's half
        int rh = rl & 127;
        int c  = w & 0x1FFFF;
        int pos = atomicAdd(&cnt[rh], 1);       // LDS atomic
        if (pos < CAP) win[(rh << 6) + pos] = c; // LDS store (fast)
    }
    __syncthreads();

    int r0 = (p << PSHIFT) + (half << 7);       // first row of this half
    int rows = n_nodes - r0;
    if (rows > RPP / 2) rows = RPP / 2;
    if (rows > 0) {
        // coalesced blast; unused slots carry garbage, never read (count
        // gates the row kernel). Clamped so tail never overruns bucket.
        int nint4 = rows * (CAP / 4);
        int4* dst = (int4*)(bucket + (long long)r0 * CAP);
        const int4* src = (const int4*)win;
        for (int i = tid; i < nint4; i += 256) dst[i] = src[i];
        if (tid < rows) count[r0 + tid] = cnt[tid];
    }
}

// ---------------- spill drain (normally empty) ----------------
__global__ void spill_drain_kernel(const long long* __restrict__ spill,
                                   const int* __restrict__ spill_cnt,
                                   int* __restrict__ count,
                                   int* __restrict__ bucket) {
    int ns = *spill_cnt; if (ns > SPILL_CAP) ns = SPILL_CAP;
    int stride = gridDim.x * blockDim.x;
    for (int t = blockIdx.x * blockDim.x + threadIdx.x; t < ns; t += stride) {
        long long wc = spill[t];
        int r = (int)(wc >> 32);
        int c = (int)(wc & 0xFFFFFFFFLL);
        int pos = atomicAdd(&count[r], 1);
        if (pos < CAP) bucket[(long long)r * CAP + pos] = c;
    }
}

// ---------------- flag-gated repair (all-exit when clean) ----------------
__global__ void repair_zero_kernel(const int* __restrict__ flag,
                                   int* __restrict__ count, int n_nodes) {
    if (*flag == 0) return;
    int t = blockIdx.x * blockDim.x + threadIdx.x;
    if (t < n_nodes) count[t] = 0;
}

__global__ void repair_scatter_kernel(const int* __restrict__ flag,
                                      const int* __restrict__ idx,
                                      int* __restrict__ count,
                                      int* __restrict__ bucket, int n_edges) {
    if (*flag == 0) return;
    int t = blockIdx.x * blockDim.x + threadIdx.x;
    if (t < n_edges) {
        int r = idx[t];
        int c = idx[n_edges + t];
        int p = atomicAdd(&count[r], 1);
        if (p < CAP) bucket[(long long)r * CAP + p] = c;
    }
}

// ---------------- tier-2 build: direct scatter (round 7) ----------------
__global__ void bucket_scatter_kernel(const int* __restrict__ idx,
                                      int* __restrict__ count,
                                      int* __restrict__ bucket, int n_edges) {
    int t = blockIdx.x * blockDim.x + threadIdx.x;
    if (t < n_edges) {
        int r = idx[t];
        int c = idx[n_edges + t];
        int p = atomicAdd(&count[r], 1);
        if (p < CAP) bucket[(long long)r * CAP + p] = c;
    }
}

// ---------------- row kernel: one wave per row, 16 edges in flight -------
__global__ void row_kernel(const float* __restrict__ q, const float* __restrict__ k,
                           const float* __restrict__ v, const float* __restrict__ eigs,
                           const float* __restrict__ lambda0,
                           const int* __restrict__ counts,
                           const int* __restrict__ col,
                           const int* __restrict__ idx, int n_edges,
                           float* __restrict__ out, int n_nodes) {
    long long tid = (long long)blockIdx.x * blockDim.x + threadIdx.x;
    int r = (int)(tid >> 6);
    if (r >= n_nodes) return;
    int lane = threadIdx.x & 63;
    int sub = lane & 15;
    int grp = lane >> 4;

    int deg = counts[r];
    const float expL = __expf(lambda0[0]);

    if (deg > CAP) {
        // overflow slow path: rescan edge list (never triggers for this input)
        float qs = q[(long long)r * HD + lane] * 0.125f;
        float gs = (lane < ED) ? eigs[(long long)r * ED + lane] * expL : 0.f;
        float accs = 0.f, den = 0.f;
        for (int base = 0; base < n_edges; base += 64) {
            int e = base + lane;
            int rr = (e < n_edges) ? idx[e] : -1;
            int cc = (e < n_edges) ? idx[n_edges + e] : 0;
            unsigned long long mm = __ballot(rr == r);
            while (mm) {
                int b = __ffsll(mm) - 1;
                mm &= mm - 1;
                int c = __shfl(cc, b, 64);
                float kb = k[(long long)c * HD + lane];
                float gb = (lane < ED) ? eigs[(long long)c * ED + lane] : 0.f;
                float s = qs * kb + gs * gb;
                #pragma unroll
                for (int off = 32; off > 0; off >>= 1) s += __shfl_xor(s, off, 64);
                float e1 = fminf(__expf(s), 5.0f);
                den += e1;
                accs += e1 * v[(long long)c * HD + lane];
            }
        }
        float inv = (den == 0.f) ? 1.f : __frcp_rn(den);
        out[(long long)r * HD + lane] = accs * inv;
        return;
    }

    long long start = (long long)r * CAP;

    float4 qa = *(const float4*)(q    + (long long)r * HD + sub * 4);
    float2 ga = *(const float2*)(eigs + (long long)r * ED + sub * 2);
    qa.x *= 0.125f; qa.y *= 0.125f; qa.z *= 0.125f; qa.w *= 0.125f;
    ga.x *= expL;   ga.y *= expL;

    float4 acc = make_float4(0.f, 0.f, 0.f, 0.f);
    float den = 0.f;

    for (int base = 0; base < deg; base += 64) {
        int m = deg - base; if (m > 64) m = 64;
        int cl = (lane < m) ? col[start + base + lane] : 0;
        for (int j = 0; j < m; j += 16) {
            // 4 edges per 16-lane group -> 12 gather loads in flight
            int c1 = __shfl(cl, j + grp,      64);
            int c2 = __shfl(cl, j + 4 + grp,  64);
            int c3 = __shfl(cl, j + 8 + grp,  64);
            int c4 = __shfl(cl, j + 12 + grp, 64);
            float4 kb1 = *(const float4*)(k    + (long long)c1 * HD + sub * 4);
            float2 gb1 = *(const float2*)(eigs + (long long)c1 * ED + sub * 2);
            float4 vv1 = *(const float4*)(v    + (long long)c1 * HD + sub * 4);
            float4 kb2 = *(const float4*)(k    + (long long)c2 * HD + sub * 4);
            float2 gb2 = *(const float2*)(eigs + (long long)c2 * ED + sub * 2);
            float4 vv2 = *(const float4*)(v    + (long long)c2 * HD + sub * 4);
            float4 kb3 = *(const float4*)(k    + (long long)c3 * HD + sub * 4);
            float2 gb3 = *(const float2*)(eigs + (long long)c3 * ED + sub * 2);
            float4 vv3 = *(const float4*)(v    + (long long)c3 * HD + sub * 4);
            float4 kb4 = *(const float4*)(k    + (long long)c4 * HD + sub * 4);
            float2 gb4 = *(const float2*)(eigs + (long long)c4 * ED + sub * 2);
            float4 vv4 = *(const float4*)(v    + (long long)c4 * HD + sub * 4);

            float s1 = qa.x*kb1.x + qa.y*kb1.y + qa.z*kb1.z + qa.w*kb1.w
                     + ga.x*gb1.x + ga.y*gb1.y;
            float s2 = qa.x*kb2.x + qa.y*kb2.y + qa.z*kb2.z + qa.w*kb2.w
                     + ga.x*gb2.x + ga.y*gb2.y;
            float s3 = qa.x*kb3.x + qa.y*kb3.y + qa.z*kb3.z + qa.w*kb3.w
                     + ga.x*gb3.x + ga.y*gb3.y;
            float s4 = qa.x*kb4.x + qa.y*kb4.y + qa.z*kb4.z + qa.w*kb4.w
                     + ga.x*gb4.x + ga.y*gb4.y;
            #pragma unroll
            for (int off = 8; off > 0; off >>= 1) {
                s1 += __shfl_xor(s1, off, 64);
                s2 += __shfl_xor(s2, off, 64);
                s3 += __shfl_xor(s3, off, 64);
                s4 += __shfl_xor(s4, off, 64);
            }
            float e1 = fminf(__expf(s1), 5.0f);
            float e2 = fminf(__expf(s2), 5.0f);
            float e3 = fminf(__expf(s3), 5.0f);
            float e4 = fminf(__expf(s4), 5.0f);

            if (j + grp < m) {
                den += e1;
                acc.x += e1 * vv1.x; acc.y += e1 * vv1.y;
                acc.z += e1 * vv1.z; acc.w += e1 * vv1.w;
            }
            if (j + 4 + grp < m) {
                den += e2;
                acc.x += e2 * vv2.x; acc.y += e2 * vv2.y;
                acc.z += e2 * vv2.z; acc.w += e2 * vv2.w;
            }
            if (j + 8 + grp < m) {
                den += e3;
                acc.x += e3 * vv3.x; acc.y += e3 * vv3.y;
                acc.z += e3 * vv3.z; acc.w += e3 * vv3.w;
            }
            if (j + 12 + grp < m) {
                den += e4;
                acc.x += e4 * vv4.x; acc.y += e4 * vv4.y;
                acc.z += e4 * vv4.z; acc.w += e4 * vv4.w;
            }
        }
    }

    #pragma unroll
    for (int off = 16; off < 64; off <<= 1) {
        acc.x += __shfl_xor(acc.x, off, 64);
        acc.y += __shfl_xor(acc.y, off, 64);
        acc.z += __shfl_xor(acc.z, off, 64);
        acc.w += __shfl_xor(acc.w, off, 64);
        den   += __shfl_xor(den,   off, 64);
    }

    if (grp == 0) {
        float inv = (den == 0.0f) ? 1.0f : __frcp_rn(den);
        float4 o = make_float4(acc.x * inv, acc.y * inv, acc.z * inv, acc.w * inv);
        *(float4*)(out + (long long)r * HD + sub * 4) = o;
    }
}

// ---------------- tier-3: round-4 fused atomic path ----------------
__global__ void edge_fused_kernel(const float* __restrict__ q,
                                  const float* __restrict__ k,
                                  const float* __restrict__ v,
                                  const float* __restrict__ eigs,
                                  const float* __restrict__ lambda0,
                                  const int* __restrict__ idx,
                                  float* __restrict__ denom,
                                  float* __restrict__ out, int n_edges) {
    long long gid = (long long)blockIdx.x * blockDim.x + threadIdx.x;
    int lane = threadIdx.x & 63;
    int edge = (int)(gid >> 4);
    int sub  = (int)(gid & 15);
    int valid = (edge < n_edges);
    int ec = valid ? edge : (n_edges - 1);
    int i0 = idx[ec];
    int i1 = idx[n_edges + ec];
    const float expL = __expf(lambda0[0]);
    float4 qa = *(const float4*)(q + (long long)i0 * HD + sub * 4);
    float4 kb = *(const float4*)(k + (long long)i1 * HD + sub * 4);
    float c = (qa.x*kb.x + qa.y*kb.y + qa.z*kb.z + qa.w*kb.w) * 0.125f;
    float2 ea = *(const float2*)(eigs + (long long)i0 * ED + sub * 2);
    float2 eb = *(const float2*)(eigs + (long long)i1 * ED + sub * 2);
    c += expL * (ea.x * eb.x + ea.y * eb.y);
    #pragma unroll
    for (int off = 8; off > 0; off >>= 1) c += __shfl_xor(c, off, 64);
    float e = fminf(__expf(c), 5.0f);
    if (valid && sub == 0) atomicAdd(&denom[i0], e);
    #pragma unroll
    for (int j = 0; j < 4; ++j) {
        float ej = __shfl(e,     j * 16, 64);
        int   r  = __shfl(i0,    j * 16, 64);
        int   s  = __shfl(i1,    j * 16, 64);
        int   vj = __shfl(valid, j * 16, 64);
        if (vj) {
            float vv = v[(long long)s * HD + lane];
            atomicAdd(&out[(long long)r * HD + lane], ej * vv);
        }
    }
}

__global__ void normalize_kernel(float* __restrict__ out,
                                 const float* __restrict__ denom, int n_nodes) {
    int t = blockIdx.x * blockDim.x + threadIdx.x;
    int total = n_nodes * (HD / 4);
    if (t >= total) return;
    int row = t >> 4;
    float d = denom[row];
    float inv = (d == 0.0f) ? 1.0f : __frcp_rn(d);
    float4* o4 = (float4*)out;
    float4 x = o4[t];
    x.x *= inv; x.y *= inv; x.z *= inv; x.w *= inv;
    o4[t] = x;
}

extern "C" void kernel_launch(void* const* d_in, const int* in_sizes, int n_in,
                              void* d_out, int out_size, void* d_ws, size_t ws_size,
                              hipStream_t stream) {
    const float* q       = (const float*)d_in[0];
    const float* k       = (const float*)d_in[1];
    const float* v       = (const float*)d_in[2];
    const float* eigs    = (const float*)d_in[3];
    const float* lambda0 = (const float*)d_in[4];
    const int*   idx     = (const int*)d_in[5];   // [2, E], int32

    const int n_edges = in_sizes[5] / 2;
    const int n_nodes = in_sizes[0] / HD;

    const int NP = (n_nodes + RPP - 1) / RPP;
    const int eb = (n_edges + 255) / 256;
    long long rthreads = (long long)n_nodes * 64;
    const int rb = (int)((rthreads + 255) / 256);

    size_t need1 = ((size_t)n_nodes + (size_t)n_nodes * CAP
                    + (size_t)NP * PCAP + NP + 2) * sizeof(int)
                 + (size_t)SPILL_CAP * sizeof(long long);
    size_t need2 = ((size_t)n_nodes + (size_t)n_nodes * CAP) * sizeof(int);

    if (ws_size >= need1) {
        // -------- tier 1: LDS-binned two-pass build --------
        int* count     = (int*)d_ws;                    // [N]
        int* bucket    = count + n_nodes;               // [N*CAP]
        int* part      = bucket + (size_t)n_nodes * CAP;// [NP*PCAP]
        int* gcur      = part + (size_t)NP * PCAP;      // [NP]
        int* spill_cnt = gcur + NP;                     // [1]
        int* flag      = spill_cnt + 1;                 // [1]
        long long* spill = (long long*)(flag + 1);      // [SPILL_CAP]

        hipMemsetAsync(gcur, 0, (size_t)(NP + 2) * sizeof(int), stream);

        int chunk = (n_edges + NB1 - 1) / NB1;
        size_t smbytes = (size_t)NP * (1 + D1) * sizeof(int);
        p1_bin_kernel<<<NB1, 256, smbytes, stream>>>(idx, n_edges, NP, chunk,
                                                     part, gcur, spill,
                                                     spill_cnt, flag);
        p2_bucket_kernel<<<2 * NP, 256, 0, stream>>>(part, gcur, count, bucket,
                                                     n_nodes);
        spill_drain_kernel<<<256, 256, 0, stream>>>(spill, spill_cnt, count,
                                                    bucket);
        repair_zero_kernel<<<(n_nodes + 255) / 256, 256, 0, stream>>>(flag, count,
                                                                      n_nodes);
        repair_scatter_kernel<<<eb, 256, 0, stream>>>(flag, idx, count, bucket,
                                                      n_edges);
        row_kernel<<<rb, 256, 0, stream>>>(q, k, v, eigs, lambda0, count, bucket,
                                           idx, n_edges, (float*)d_out, n_nodes);
    } else if (ws_size >= need2) {
        // -------- tier 2: direct scatter (round 7) --------
        int* count  = (int*)d_ws;
        int* bucket = count + n_nodes;
        hipMemsetAsync(count, 0, (size_t)n_nodes * sizeof(int), stream);
        bucket_scatter_kernel<<<eb, 256, 0, stream>>>(idx, count, bucket, n_edges);
        row_kernel<<<rb, 256, 0, stream>>>(q, k, v, eigs, lambda0, count, bucket,
                                           idx, n_edges, (float*)d_out, n_nodes);
    } else {
        // -------- tier 3: fused atomic path (round 4) --------
        float* denom = (float*)d_ws;   // [N]
        hipMemsetAsync(denom, 0, (size_t)n_nodes * sizeof(float), stream);
        hipMemsetAsync(d_out, 0, (size_t)out_size * sizeof(float), stream);
        long long threads = (long long)n_edges * 16;
        int grid = (int)((threads + 255) / 256);
        edge_fused_kernel<<<grid, 256, 0, stream>>>(q, k, v, eigs, lambda0, idx,
                                                    denom, (float*)d_out, n_edges);
        int n4 = n_nodes * (HD / 4);
        normalize_kernel<<<(n4 + 255) / 256, 256, 0, stream>>>((float*)d_out,
                                                               denom, n_nodes);
    }
}